// Round 7
// baseline (1011.690 us; speedup 1.0000x reference)
//
#include <hip/hip_runtime.h>
#include <hip/hip_bf16.h>
#include <cstdint>

typedef __attribute__((ext_vector_type(8))) short short8;
typedef __attribute__((ext_vector_type(4))) float floatx4;
typedef unsigned short u16;
typedef unsigned int u32;

#define SCALE_F 0.0625f
#define LN_EPS_F 1e-5f
#define NEG_BIG (-3.0e38f)

__device__ __forceinline__ u16 f32_to_bf16(float f) {
    union { float f; u32 u; } v; v.f = f;
    u32 u = v.u;
    return (u16)((u + 0x7FFFu + ((u >> 16) & 1u)) >> 16);
}
__device__ __forceinline__ float bf_lo(u32 u){ union{u32 x; float f;} v; v.x = u << 16; return v.f; }
__device__ __forceinline__ float bf_hi(u32 u){ union{u32 x; float f;} v; v.x = u & 0xFFFF0000u; return v.f; }
__device__ __forceinline__ u32 cvt_pk2(float lo, float hi) {
    u32 r; asm volatile("v_cvt_pk_bf16_f32 %0, %1, %2" : "=v"(r) : "v"(lo), "v"(hi)); return r;
}

// ---------------- prep: slot init + all weight repacks ----------------
__global__ __launch_bounds__(256) void k_prep(
        const float* __restrict__ noise, const float* __restrict__ mu, const float* __restrict__ lsig,
        const float* __restrict__ Wq, const float* __restrict__ Wk, const float* __restrict__ Wv,
        const float* __restrict__ W_ih, const float* __restrict__ W_hh,
        const float* __restrict__ W1, const float* __restrict__ W2,
        float* __restrict__ slots, u16* __restrict__ w_t,
        u32* __restrict__ wqp, u32* __restrict__ wgh, u32* __restrict__ w1p, u32* __restrict__ w2p) {
    int i = blockIdx.x * 256 + threadIdx.x;
    if (i < 262144) {
        int d = i & 255;
        slots[i] = mu[d] + expf(lsig[d]) * noise[i];
    } else if (i < 393216) {
        int j = i - 262144; int c = j >> 8, k = j & 255;
        float w = (c < 256) ? Wk[k*256 + c] : Wv[k*256 + (c - 256)];
        w_t[j] = f32_to_bf16(w);
    } else if (i < 425984) {
        int j = i - 393216; int d2 = j >> 8, t = j & 255;
        wqp[j] = cvt_pk2(Wq[(2*d2)*256 + t], Wq[(2*d2+1)*256 + t]);
    } else if (i < 622592) {
        int j = i - 425984;
        wgh[j] = cvt_pk2(W_ih[j], W_hh[j]);
    } else if (i < 688128) {
        int j = i - 622592; int d = j >> 8, t = j & 255;
        w1p[j] = cvt_pk2(W1[d*512 + t], W1[d*512 + t + 256]);
    } else if (i < 753664) {
        int j = i - 688128; int d2 = j >> 8, t = j & 255;
        w2p[j] = cvt_pk2(W2[(2*d2)*256 + t], W2[(2*d2+1)*256 + t]);
    }
}

// ---------------- k/v projection GEMM (R3 exact: proven passing, 211 us) ----------------
// 256 thr / 4 waves. Block: 64 rows x 512 cols, K=256 in 4 tiles of 64.
// B (weights, 256KB, L2-hot) -> registers directly (no LDS). A -> 2x8KB LDS dbuf.
// MFMA operands swapped: mfma(w_frag, x_frag) -> lane holds 4 consecutive out-cols.
__global__ __launch_bounds__(256, 2) void k_gemm_kv(const float* __restrict__ X,
        const u16* __restrict__ w_t, u16* __restrict__ kbf, u16* __restrict__ vbf) {
    __shared__ __align__(16) unsigned char a_lds[2][8192];   // [64 rows][64 k] bf16, XOR-swizzled
    const int tid = threadIdx.x;
    const int lane = tid & 63;
    const int w = tid >> 6;              // wave -> col strip w*128
    const long rb = blockIdx.x;          // 0..4095 row-blocks of 64
    const int l4 = lane >> 4, l15 = lane & 15;

    const int srow = tid >> 2, skq = tid & 3;
    const float* xbase = X + (rb * 64 + srow) * 256 + skq * 16;

    floatx4 acc[4][8];                   // [mf][nf]
    #pragma unroll
    for (int mf = 0; mf < 4; mf++)
        #pragma unroll
        for (int nf = 0; nf < 8; nf++)
            acc[mf][nf] = (floatx4){0.f, 0.f, 0.f, 0.f};

    // prologue: stage A tile kt=0
    {
        float4 f0 = *reinterpret_cast<const float4*>(xbase);
        float4 f1 = *reinterpret_cast<const float4*>(xbase + 4);
        float4 f2 = *reinterpret_cast<const float4*>(xbase + 8);
        float4 f3 = *reinterpret_cast<const float4*>(xbase + 12);
        uint4 v0, v1;
        v0.x = cvt_pk2(f0.x, f0.y); v0.y = cvt_pk2(f0.z, f0.w);
        v0.z = cvt_pk2(f1.x, f1.y); v0.w = cvt_pk2(f1.z, f1.w);
        v1.x = cvt_pk2(f2.x, f2.y); v1.y = cvt_pk2(f2.z, f2.w);
        v1.z = cvt_pk2(f3.x, f3.y); v1.w = cvt_pk2(f3.z, f3.w);
        int g0 = skq * 2, g1 = skq * 2 + 1, sx = (srow & 7) << 4;
        *reinterpret_cast<uint4*>(&a_lds[0][srow * 128 + ((g0 * 16) ^ sx)]) = v0;
        *reinterpret_cast<uint4*>(&a_lds[0][srow * 128 + ((g1 * 16) ^ sx)]) = v1;
    }
    __syncthreads();

    const u16* wbase = w_t + (w * 128 + l15) * 256 + l4 * 8;  // + nf*16*256 + k0

    int cur = 0;
    #pragma unroll
    for (int kt = 0; kt < 4; kt++) {
        short8 wf0[8], wf1[8];
        #pragma unroll
        for (int nf = 0; nf < 8; nf++)
            wf0[nf] = *reinterpret_cast<const short8*>(wbase + (long)nf * 4096 + kt * 64);
        float4 f0, f1, f2, f3;
        if (kt < 3) {
            const float* sp = xbase + (kt + 1) * 64;
            f0 = *reinterpret_cast<const float4*>(sp);
            f1 = *reinterpret_cast<const float4*>(sp + 4);
            f2 = *reinterpret_cast<const float4*>(sp + 8);
            f3 = *reinterpret_cast<const float4*>(sp + 12);
        }
        #pragma unroll
        for (int nf = 0; nf < 8; nf++)
            wf1[nf] = *reinterpret_cast<const short8*>(wbase + (long)nf * 4096 + kt * 64 + 32);
        // ks = 0
        {
            short8 xf[4];
            #pragma unroll
            for (int mf = 0; mf < 4; mf++) {
                int row = mf * 16 + l15;
                int g = 0 * 4 + l4;
                xf[mf] = *reinterpret_cast<const short8*>(&a_lds[cur][row * 128 + ((g * 16) ^ ((row & 7) << 4))]);
            }
            #pragma unroll
            for (int mf = 0; mf < 4; mf++)
                #pragma unroll
                for (int nf = 0; nf < 8; nf++)
                    acc[mf][nf] = __builtin_amdgcn_mfma_f32_16x16x32_bf16(wf0[nf], xf[mf], acc[mf][nf], 0, 0, 0);
        }
        // ks = 1
        {
            short8 xf[4];
            #pragma unroll
            for (int mf = 0; mf < 4; mf++) {
                int row = mf * 16 + l15;
                int g = 1 * 4 + l4;
                xf[mf] = *reinterpret_cast<const short8*>(&a_lds[cur][row * 128 + ((g * 16) ^ ((row & 7) << 4))]);
            }
            #pragma unroll
            for (int mf = 0; mf < 4; mf++)
                #pragma unroll
                for (int nf = 0; nf < 8; nf++)
                    acc[mf][nf] = __builtin_amdgcn_mfma_f32_16x16x32_bf16(wf1[nf], xf[mf], acc[mf][nf], 0, 0, 0);
        }
        if (kt < 3) {
            __syncthreads();   // everyone done reading a_lds[cur]
            uint4 v0, v1;
            v0.x = cvt_pk2(f0.x, f0.y); v0.y = cvt_pk2(f0.z, f0.w);
            v0.z = cvt_pk2(f1.x, f1.y); v0.w = cvt_pk2(f1.z, f1.w);
            v1.x = cvt_pk2(f2.x, f2.y); v1.y = cvt_pk2(f2.z, f2.w);
            v1.z = cvt_pk2(f3.x, f3.y); v1.w = cvt_pk2(f3.z, f3.w);
            int g0 = skq * 2, g1 = skq * 2 + 1, sx = (srow & 7) << 4;
            *reinterpret_cast<uint4*>(&a_lds[cur ^ 1][srow * 128 + ((g0 * 16) ^ sx)]) = v0;
            *reinterpret_cast<uint4*>(&a_lds[cur ^ 1][srow * 128 + ((g1 * 16) ^ sx)]) = v1;
            __syncthreads();   // writes visible
            cur ^= 1;
        }
    }

    // epilogue: out-row = x-row (l15), out-col = w-col (4 consecutive per reg)
    const int nt = l4 & 1, half = l4 >> 1;
    #pragma unroll
    for (int mf = 0; mf < 4; mf++)
        #pragma unroll
        for (int p = 0; p < 4; p++) {     // nf pair (2p, 2p+1)
            u32 pn[2][2], po[2][2];
            #pragma unroll
            for (int n = 0; n < 2; n++) {
                int nf = p * 2 + n;
                pn[n][0] = cvt_pk2(acc[mf][nf][0], acc[mf][nf][1]);
                pn[n][1] = cvt_pk2(acc[mf][nf][2], acc[mf][nf][3]);
                po[n][0] = (u32)__shfl_xor((int)pn[n][0], 16);
                po[n][1] = (u32)__shfl_xor((int)pn[n][1], 16);
            }
            u32 a0 = pn[nt][0], a1 = pn[nt][1], b0 = po[nt][0], b1 = po[nt][1];
            uint4 qv;
            if (l4 & 1) { qv.x = b0; qv.y = b1; qv.z = a0; qv.w = a1; }
            else        { qv.x = a0; qv.y = a1; qv.z = b0; qv.w = b1; }
            long row_g = rb * 64 + mf * 16 + l15;
            int c0 = w * 128 + p * 32 + nt * 16 + half * 8;
            if (c0 < 256) *reinterpret_cast<uint4*>(&kbf[row_g * 256 + c0]) = qv;
            else          *reinterpret_cast<uint4*>(&vbf[row_g * 256 + c0 - 256]) = qv;
        }
}

// ---------------- initial q = SCALE * slots @ Wq (bf16 packed weights) ----------------
__global__ __launch_bounds__(256) void k_qproj(const float* __restrict__ slots,
        const u32* __restrict__ wqp, float* __restrict__ q) {
    __shared__ float s_lds[256];
    int row = blockIdx.x, t = threadIdx.x;
    s_lds[t] = slots[(long)row * 256 + t];
    __syncthreads();
    float a = 0.f;
    #pragma unroll 8
    for (int d2 = 0; d2 < 128; d2++) {
        u32 w = wqp[d2 * 256 + t];
        a += bf_lo(w) * s_lds[2*d2] + bf_hi(w) * s_lds[2*d2 + 1];
    }
    q[(long)row * 256 + t] = a * SCALE_F;
}

// ---------------- fused flash attention (reg-staged async prefetch, T14) ----------------
// grid (16 mc, 64 b) x 256 thr. Tile t+1's global loads are issued BEFORE tile t's
// compute (latency hides under QK/PV); ds_write after barrier. LDS layout identical
// to the proven gload version: k granule g at LDS slot g^(r&7), v linear.
__global__ __launch_bounds__(256) void k_flash(const float* __restrict__ q,
        const u16* __restrict__ kbf, const u16* __restrict__ vbf,
        float* __restrict__ part, float* __restrict__ ml) {
    __shared__ __align__(16) float q_lds[16 * 256];
    __shared__ __align__(16) u16 k_lds[32 * 256];
    __shared__ __align__(16) u16 v_lds[32 * 256];
    __shared__ float p_lds[4 * 32 * 4];
    const int b = blockIdx.y, mc = blockIdx.x, tid = threadIdx.x;
    const int w = tid >> 6, l = tid & 63, m = l & 31, np = l >> 5;
    const int n_base = w * 4 + np * 2;
    #pragma unroll
    for (int it = 0; it < 4; it++) {
        int gid = tid + it * 256;
        *reinterpret_cast<float4*>(&q_lds[gid * 4]) =
            *reinterpret_cast<const float4*>(&q[(long)b * 4096 + gid * 4]);
    }
    const long kv_base = (long)b * 4096 + mc * 256;
    float mrun0 = NEG_BIG, mrun1 = NEG_BIG, lrun0 = 0.f, lrun1 = 0.f;
    float acc[16];
    #pragma unroll
    for (int k = 0; k < 16; k++) acc[k] = 0.f;
    const float* qp0 = &q_lds[n_base * 256];
    const float* qp1 = qp0 + 256;

    uint4 kreg[4], vreg[4];
#define FLOAD(t) { _Pragma("unroll") for (int it = 0; it < 4; it++) { \
        int gid = tid + it * 256; int r_ = gid >> 5, gp_ = gid & 31; \
        kreg[it] = *reinterpret_cast<const uint4*>(kbf + (kv_base + (t) * 32 + r_) * 256 + gp_ * 8); \
        vreg[it] = *reinterpret_cast<const uint4*>(vbf + (kv_base + (t) * 32 + r_) * 256 + gp_ * 8); } }
#define FWRITE() { _Pragma("unroll") for (int it = 0; it < 4; it++) { \
        int gid = tid + it * 256; int r_ = gid >> 5, gp_ = gid & 31; \
        *reinterpret_cast<uint4*>(&k_lds[r_ * 256 + (((gp_ * 16) ^ ((r_ & 7) << 4)) >> 1)]) = kreg[it]; \
        *reinterpret_cast<uint4*>(&v_lds[r_ * 256 + gp_ * 8]) = vreg[it]; } }

    FLOAD(0); FWRITE();
    __syncthreads();

    for (int t = 0; t < 8; t++) {
        if (t < 7) FLOAD(t + 1);   // in flight during this tile's compute
        float s0 = 0.f, s1 = 0.f;
        #pragma unroll 4
        for (int d0 = 0; d0 < 256; d0 += 8) {
            int off = m * 256 + ((((d0 >> 3) * 16) ^ ((m & 7) << 4)) >> 1);
            uint4 kv = *reinterpret_cast<const uint4*>(&k_lds[off]);
            float kf0 = bf_lo(kv.x), kf1 = bf_hi(kv.x), kf2 = bf_lo(kv.y), kf3 = bf_hi(kv.y);
            float kf4 = bf_lo(kv.z), kf5 = bf_hi(kv.z), kf6 = bf_lo(kv.w), kf7 = bf_hi(kv.w);
            float4 qa = *reinterpret_cast<const float4*>(qp0 + d0);
            float4 qb = *reinterpret_cast<const float4*>(qp0 + d0 + 4);
            float4 qc = *reinterpret_cast<const float4*>(qp1 + d0);
            float4 qd = *reinterpret_cast<const float4*>(qp1 + d0 + 4);
            s0 += qa.x*kf0 + qa.y*kf1 + qa.z*kf2 + qa.w*kf3 + qb.x*kf4 + qb.y*kf5 + qb.z*kf6 + qb.w*kf7;
            s1 += qc.x*kf0 + qc.y*kf1 + qc.z*kf2 + qc.w*kf3 + qd.x*kf4 + qd.y*kf5 + qd.z*kf6 + qd.w*kf7;
        }
        float mx0 = s0, mx1 = s1;
        #pragma unroll
        for (int off = 1; off <= 16; off <<= 1) {
            mx0 = fmaxf(mx0, __shfl_xor(mx0, off));
            mx1 = fmaxf(mx1, __shfl_xor(mx1, off));
        }
        float mn0 = fmaxf(mrun0, mx0), mn1 = fmaxf(mrun1, mx1);
        float sc0 = __expf(mrun0 - mn0), sc1 = __expf(mrun1 - mn1);
        float p0 = __expf(s0 - mn0), p1 = __expf(s1 - mn1);
        float ps0 = p0, ps1 = p1;
        #pragma unroll
        for (int off = 1; off <= 16; off <<= 1) {
            ps0 += __shfl_xor(ps0, off);
            ps1 += __shfl_xor(ps1, off);
        }
        lrun0 = lrun0 * sc0 + ps0; lrun1 = lrun1 * sc1 + ps1;
        mrun0 = mn0; mrun1 = mn1;
        #pragma unroll
        for (int k = 0; k < 8; k++) { acc[k] *= sc0; acc[8 + k] *= sc1; }
        p_lds[w * 128 + m * 4 + np * 2 + 0] = p0;
        p_lds[w * 128 + m * 4 + np * 2 + 1] = p1;
        asm volatile("s_waitcnt lgkmcnt(0)" ::: "memory");
        #pragma unroll 4
        for (int mi = 0; mi < 32; mi++) {
            float2 pp = *reinterpret_cast<const float2*>(&p_lds[w * 128 + mi * 4 + np * 2]);
            uint4 vv = *reinterpret_cast<const uint4*>(&v_lds[mi * 256 + m * 8]);
            float vf0 = bf_lo(vv.x), vf1 = bf_hi(vv.x), vf2 = bf_lo(vv.y), vf3 = bf_hi(vv.y);
            float vf4 = bf_lo(vv.z), vf5 = bf_hi(vv.z), vf6 = bf_lo(vv.w), vf7 = bf_hi(vv.w);
            acc[0] += pp.x*vf0; acc[1] += pp.x*vf1; acc[2] += pp.x*vf2; acc[3] += pp.x*vf3;
            acc[4] += pp.x*vf4; acc[5] += pp.x*vf5; acc[6] += pp.x*vf6; acc[7] += pp.x*vf7;
            acc[8] += pp.y*vf0; acc[9] += pp.y*vf1; acc[10]+= pp.y*vf2; acc[11]+= pp.y*vf3;
            acc[12]+= pp.y*vf4; acc[13]+= pp.y*vf5; acc[14]+= pp.y*vf6; acc[15]+= pp.y*vf7;
        }
        __syncthreads();             // all reads of tile t done
        if (t < 7) FWRITE();         // publish tile t+1 (waits vmcnt internally)
        __syncthreads();             // writes visible
    }
#undef FLOAD
#undef FWRITE
    #pragma unroll
    for (int j = 0; j < 2; j++) {
        int n = n_base + j;
        long po = ((long)(b * 16 + mc) * 16 + n) * 256 + m * 8;
        float4 f0, f1;
        f0.x = acc[j*8+0]; f0.y = acc[j*8+1]; f0.z = acc[j*8+2]; f0.w = acc[j*8+3];
        f1.x = acc[j*8+4]; f1.y = acc[j*8+5]; f1.z = acc[j*8+6]; f1.w = acc[j*8+7];
        *reinterpret_cast<float4*>(&part[po]) = f0;
        *reinterpret_cast<float4*>(&part[po + 4]) = f1;
    }
    if (m == 0) {
        int base = ((b * 16 + mc) * 16 + n_base) * 2;
        ml[base + 0] = mrun0; ml[base + 1] = lrun0;
        ml[base + 2] = mrun1; ml[base + 3] = lrun1;
    }
}

// ---------------- fused merge + GRU + LayerNorm + MLP residual + next-q; 2 rows/block ----------------
__global__ __launch_bounds__(256) void k_gru(const float* __restrict__ part, const float* __restrict__ ml,
        float* __restrict__ slots,
        const u32* __restrict__ wgh, const float* __restrict__ b_ih, const float* __restrict__ b_hh,
        const float* __restrict__ ln_g, const float* __restrict__ ln_b,
        const u32* __restrict__ w1p, const float* __restrict__ b1,
        const u32* __restrict__ w2p, const float* __restrict__ b2,
        const u32* __restrict__ wqp, float* __restrict__ qout) {
    __shared__ float u_lds[2][256], s_lds[2][256], h_lds[2][256], hm_lds[2][512], sf_lds[2][256];
    __shared__ float red[2][4][2];
    int t = threadIdx.x;
    int row0 = blockIdx.x * 2;
    int b = row0 >> 4, n0 = row0 & 15;
    #pragma unroll
    for (int rr = 0; rr < 2; rr++) {
        int n = n0 + rr;
        const float* mlp = ml + ((long)b * 256 + n) * 2;
        float M = NEG_BIG;
        float mv[16], lv[16];
        #pragma unroll
        for (int c = 0; c < 16; c++) { mv[c] = mlp[c * 32]; lv[c] = mlp[c * 32 + 1]; M = fmaxf(M, mv[c]); }
        float ec[16], denom = 0.f;
        #pragma unroll
        for (int c = 0; c < 16; c++) { ec[c] = __expf(mv[c] - M); denom += ec[c] * lv[c]; }
        float inv = 1.f / denom;
        float u = 0.f;
        #pragma unroll
        for (int c = 0; c < 16; c++)
            u += part[(((long)b * 16 + c) * 16 + n) * 256 + t] * ec[c];
        u_lds[rr][t] = u * inv;
        s_lds[rr][t] = slots[(long)(row0 + rr) * 256 + t];
    }
    __syncthreads();
    float gxr[2] = {0,0}, gxz[2] = {0,0}, gxn[2] = {0,0};
    float ghr[2] = {0,0}, ghz[2] = {0,0}, ghn[2] = {0,0};
    #pragma unroll 4
    for (int d = 0; d < 256; d++) {
        u32 p0 = wgh[d * 768 + t], p1 = wgh[d * 768 + 256 + t], p2 = wgh[d * 768 + 512 + t];
        float wir = bf_lo(p0), whr = bf_hi(p0);
        float wiz = bf_lo(p1), whz = bf_hi(p1);
        float win = bf_lo(p2), whn = bf_hi(p2);
        #pragma unroll
        for (int rr = 0; rr < 2; rr++) {
            float ud = u_lds[rr][d], sd = s_lds[rr][d];
            gxr[rr] += ud * wir; ghr[rr] += sd * whr;
            gxz[rr] += ud * wiz; ghz[rr] += sd * whz;
            gxn[rr] += ud * win; ghn[rr] += sd * whn;
        }
    }
    float bir = b_ih[t], biz = b_ih[t + 256], bin = b_ih[t + 512];
    float bhr = b_hh[t], bhz = b_hh[t + 256], bhn = b_hh[t + 512];
    float snew[2];
    int wv = t >> 6, lnid = t & 63;
    #pragma unroll
    for (int rr = 0; rr < 2; rr++) {
        float r = 1.f / (1.f + expf(-(gxr[rr] + bir + ghr[rr] + bhr)));
        float z = 1.f / (1.f + expf(-(gxz[rr] + biz + ghz[rr] + bhz)));
        float nn = tanhf(gxn[rr] + bin + r * (ghn[rr] + bhn));
        snew[rr] = (1.f - z) * nn + z * s_lds[rr][t];
        float sm = snew[rr], sq = snew[rr] * snew[rr];
        #pragma unroll
        for (int off = 32; off > 0; off >>= 1) { sm += __shfl_xor(sm, off); sq += __shfl_xor(sq, off); }
        if (lnid == 0) { red[rr][wv][0] = sm; red[rr][wv][1] = sq; }
    }
    __syncthreads();
    float lng = ln_g[t], lnb = ln_b[t];
    #pragma unroll
    for (int rr = 0; rr < 2; rr++) {
        float sm = red[rr][0][0] + red[rr][1][0] + red[rr][2][0] + red[rr][3][0];
        float sq = red[rr][0][1] + red[rr][1][1] + red[rr][2][1] + red[rr][3][1];
        float mu = sm * (1.f / 256.f);
        float var = sq * (1.f / 256.f) - mu * mu;
        float rs = rsqrtf(var + LN_EPS_F);
        h_lds[rr][t] = (snew[rr] - mu) * rs * lng + lnb;
    }
    __syncthreads();
    float m1a[2] = {0,0}, m1b[2] = {0,0};
    #pragma unroll 4
    for (int d = 0; d < 256; d++) {
        u32 wp = w1p[d * 256 + t];
        float wa = bf_lo(wp), wb = bf_hi(wp);
        #pragma unroll
        for (int rr = 0; rr < 2; rr++) { float hd = h_lds[rr][d]; m1a[rr] += hd * wa; m1b[rr] += hd * wb; }
    }
    float b1a = b1[t], b1b = b1[t + 256];
    #pragma unroll
    for (int rr = 0; rr < 2; rr++) {
        float xa = m1a[rr] + b1a, xb = m1b[rr] + b1b;
        hm_lds[rr][t]       = 0.5f * xa * (1.f + erff(xa * 0.70710678118654752f));
        hm_lds[rr][t + 256] = 0.5f * xb * (1.f + erff(xb * 0.70710678118654752f));
    }
    __syncthreads();
    float m2[2] = {0,0};
    #pragma unroll 4
    for (int d2 = 0; d2 < 256; d2++) {
        u32 wp = w2p[d2 * 256 + t];
        #pragma unroll
        for (int rr = 0; rr < 2; rr++)
            m2[rr] += bf_lo(wp) * hm_lds[rr][2*d2] + bf_hi(wp) * hm_lds[rr][2*d2 + 1];
    }
    float b2v = b2[t];
    #pragma unroll
    for (int rr = 0; rr < 2; rr++) {
        float sf = snew[rr] + m2[rr] + b2v;
        slots[(long)(row0 + rr) * 256 + t] = sf;
        sf_lds[rr][t] = sf;
    }
    __syncthreads();
    float qa[2] = {0,0};
    #pragma unroll 4
    for (int d2 = 0; d2 < 128; d2++) {
        u32 wp = wqp[d2 * 256 + t];
        #pragma unroll
        for (int rr = 0; rr < 2; rr++)
            qa[rr] += bf_lo(wp) * sf_lds[rr][2*d2] + bf_hi(wp) * sf_lds[rr][2*d2 + 1];
    }
    #pragma unroll
    for (int rr = 0; rr < 2; rr++)
        qout[(long)(row0 + rr) * 256 + t] = qa[rr] * SCALE_F;
}

extern "C" void kernel_launch(void* const* d_in, const int* in_sizes, int n_in,
                              void* d_out, int out_size, void* d_ws, size_t ws_size,
                              hipStream_t stream) {
    const float* inputs  = (const float*)d_in[0];
    const float* noise   = (const float*)d_in[1];
    const float* slot_mu = (const float*)d_in[2];
    const float* slot_ls = (const float*)d_in[3];
    const float* Wq   = (const float*)d_in[4];
    const float* Wk   = (const float*)d_in[5];
    const float* Wv   = (const float*)d_in[6];
    const float* W_ih = (const float*)d_in[7];
    const float* W_hh = (const float*)d_in[8];
    const float* b_ih = (const float*)d_in[9];
    const float* b_hh = (const float*)d_in[10];
    const float* ln_g = (const float*)d_in[11];
    const float* ln_b = (const float*)d_in[12];
    const float* W1   = (const float*)d_in[13];
    const float* b1   = (const float*)d_in[14];
    const float* W2   = (const float*)d_in[15];
    const float* b2   = (const float*)d_in[16];
    float* slots = (float*)d_out;

    char* ws = (char*)d_ws;
    u16*   kbf  = (u16*)  (ws);                    // 134217728
    u16*   vbf  = (u16*)  (ws + 134217728);        // 134217728
    float* q    = (float*)(ws + 268435456);        // 1048576
    float* part = (float*)(ws + 269484032);        // 16777216
    float* ml   = (float*)(ws + 286261248);        // 131072
    u16*   w_t  = (u16*)  (ws + 286392320);        // 262144
    u32*   wgh  = (u32*)  (ws + 286654464);        // 786432
    u32*   wqp  = (u32*)  (ws + 287440896);        // 131072
    u32*   w1p  = (u32*)  (ws + 287571968);        // 262144
    u32*   w2p  = (u32*)  (ws + 287834112);        // 262144

    k_prep<<<dim3(2944), dim3(256), 0, stream>>>(noise, slot_mu, slot_ls, Wq, Wk, Wv,
            W_ih, W_hh, W1, W2, slots, w_t, wqp, wgh, w1p, w2p);
    k_gemm_kv<<<dim3(4096), dim3(256), 0, stream>>>(inputs, w_t, kbf, vbf);
    k_qproj<<<dim3(1024), dim3(256), 0, stream>>>(slots, wqp, q);
    for (int it = 0; it < 3; it++) {
        k_flash<<<dim3(16, 64), dim3(256), 0, stream>>>(q, kbf, vbf, part, ml);
        k_gru<<<dim3(512), dim3(256), 0, stream>>>(part, ml, slots,
                wgh, b_ih, b_hh, ln_g, ln_b, w1p, b1, w2p, b2, wqp, q);
    }
}

// Round 8
// 646.252 us; speedup vs baseline: 1.5655x; 1.5655x over previous
//
#include <hip/hip_runtime.h>
#include <hip/hip_bf16.h>
#include <cstdint>

typedef __attribute__((ext_vector_type(8))) short short8;
typedef __attribute__((ext_vector_type(4))) float floatx4;
typedef unsigned short u16;
typedef unsigned int u32;

#define SCALE_F 0.0625f
#define LN_EPS_F 1e-5f
#define NEG_BIG (-3.0e38f)

__device__ __forceinline__ u16 f32_to_bf16(float f) {
    union { float f; u32 u; } v; v.f = f;
    u32 u = v.u;
    return (u16)((u + 0x7FFFu + ((u >> 16) & 1u)) >> 16);
}
__device__ __forceinline__ float bf_lo(u32 u){ union{u32 x; float f;} v; v.x = u << 16; return v.f; }
__device__ __forceinline__ float bf_hi(u32 u){ union{u32 x; float f;} v; v.x = u & 0xFFFF0000u; return v.f; }
__device__ __forceinline__ u32 cvt_pk2(float lo, float hi) {
    u32 r; asm volatile("v_cvt_pk_bf16_f32 %0, %1, %2" : "=v"(r) : "v"(lo), "v"(hi)); return r;
}
__device__ __forceinline__ void gload16(const void* gsrc, void* ldst) {
    __builtin_amdgcn_global_load_lds((const __attribute__((address_space(1))) u32*)gsrc,
                                     (__attribute__((address_space(3))) u32*)ldst, 16, 0, 0);
}

// ---------------- prep: slot init + all weight repacks ----------------
__global__ __launch_bounds__(256) void k_prep(
        const float* __restrict__ noise, const float* __restrict__ mu, const float* __restrict__ lsig,
        const float* __restrict__ Wq, const float* __restrict__ Wk, const float* __restrict__ Wv,
        const float* __restrict__ W_ih, const float* __restrict__ W_hh,
        const float* __restrict__ W1, const float* __restrict__ W2,
        float* __restrict__ slots, u16* __restrict__ w_t,
        u32* __restrict__ wqp, u32* __restrict__ wgh, u32* __restrict__ w1p, u32* __restrict__ w2p) {
    int i = blockIdx.x * 256 + threadIdx.x;
    if (i < 262144) {
        int d = i & 255;
        slots[i] = mu[d] + expf(lsig[d]) * noise[i];
    } else if (i < 393216) {
        int j = i - 262144; int c = j >> 8, k = j & 255;
        float w = (c < 256) ? Wk[k*256 + c] : Wv[k*256 + (c - 256)];
        w_t[j] = f32_to_bf16(w);
    } else if (i < 425984) {
        int j = i - 393216; int d2 = j >> 8, t = j & 255;
        wqp[j] = cvt_pk2(Wq[(2*d2)*256 + t], Wq[(2*d2+1)*256 + t]);
    } else if (i < 622592) {
        int j = i - 425984;
        wgh[j] = cvt_pk2(W_ih[j], W_hh[j]);
    } else if (i < 688128) {
        int j = i - 622592; int d = j >> 8, t = j & 255;
        w1p[j] = cvt_pk2(W1[d*512 + t], W1[d*512 + t + 256]);
    } else if (i < 753664) {
        int j = i - 688128; int d2 = j >> 8, t = j & 255;
        w2p[j] = cvt_pk2(W2[(2*d2)*256 + t], W2[(2*d2+1)*256 + t]);
    }
}

// ---------------- k/v projection GEMM (R3 exact: proven passing, 211 us) ----------------
__global__ __launch_bounds__(256, 2) void k_gemm_kv(const float* __restrict__ X,
        const u16* __restrict__ w_t, u16* __restrict__ kbf, u16* __restrict__ vbf) {
    __shared__ __align__(16) unsigned char a_lds[2][8192];
    const int tid = threadIdx.x;
    const int lane = tid & 63;
    const int w = tid >> 6;
    const long rb = blockIdx.x;
    const int l4 = lane >> 4, l15 = lane & 15;

    const int srow = tid >> 2, skq = tid & 3;
    const float* xbase = X + (rb * 64 + srow) * 256 + skq * 16;

    floatx4 acc[4][8];
    #pragma unroll
    for (int mf = 0; mf < 4; mf++)
        #pragma unroll
        for (int nf = 0; nf < 8; nf++)
            acc[mf][nf] = (floatx4){0.f, 0.f, 0.f, 0.f};

    {
        float4 f0 = *reinterpret_cast<const float4*>(xbase);
        float4 f1 = *reinterpret_cast<const float4*>(xbase + 4);
        float4 f2 = *reinterpret_cast<const float4*>(xbase + 8);
        float4 f3 = *reinterpret_cast<const float4*>(xbase + 12);
        uint4 v0, v1;
        v0.x = cvt_pk2(f0.x, f0.y); v0.y = cvt_pk2(f0.z, f0.w);
        v0.z = cvt_pk2(f1.x, f1.y); v0.w = cvt_pk2(f1.z, f1.w);
        v1.x = cvt_pk2(f2.x, f2.y); v1.y = cvt_pk2(f2.z, f2.w);
        v1.z = cvt_pk2(f3.x, f3.y); v1.w = cvt_pk2(f3.z, f3.w);
        int g0 = skq * 2, g1 = skq * 2 + 1, sx = (srow & 7) << 4;
        *reinterpret_cast<uint4*>(&a_lds[0][srow * 128 + ((g0 * 16) ^ sx)]) = v0;
        *reinterpret_cast<uint4*>(&a_lds[0][srow * 128 + ((g1 * 16) ^ sx)]) = v1;
    }
    __syncthreads();

    const u16* wbase = w_t + (w * 128 + l15) * 256 + l4 * 8;

    int cur = 0;
    #pragma unroll
    for (int kt = 0; kt < 4; kt++) {
        short8 wf0[8], wf1[8];
        #pragma unroll
        for (int nf = 0; nf < 8; nf++)
            wf0[nf] = *reinterpret_cast<const short8*>(wbase + (long)nf * 4096 + kt * 64);
        float4 f0, f1, f2, f3;
        if (kt < 3) {
            const float* sp = xbase + (kt + 1) * 64;
            f0 = *reinterpret_cast<const float4*>(sp);
            f1 = *reinterpret_cast<const float4*>(sp + 4);
            f2 = *reinterpret_cast<const float4*>(sp + 8);
            f3 = *reinterpret_cast<const float4*>(sp + 12);
        }
        #pragma unroll
        for (int nf = 0; nf < 8; nf++)
            wf1[nf] = *reinterpret_cast<const short8*>(wbase + (long)nf * 4096 + kt * 64 + 32);
        {
            short8 xf[4];
            #pragma unroll
            for (int mf = 0; mf < 4; mf++) {
                int row = mf * 16 + l15;
                int g = 0 * 4 + l4;
                xf[mf] = *reinterpret_cast<const short8*>(&a_lds[cur][row * 128 + ((g * 16) ^ ((row & 7) << 4))]);
            }
            #pragma unroll
            for (int mf = 0; mf < 4; mf++)
                #pragma unroll
                for (int nf = 0; nf < 8; nf++)
                    acc[mf][nf] = __builtin_amdgcn_mfma_f32_16x16x32_bf16(wf0[nf], xf[mf], acc[mf][nf], 0, 0, 0);
        }
        {
            short8 xf[4];
            #pragma unroll
            for (int mf = 0; mf < 4; mf++) {
                int row = mf * 16 + l15;
                int g = 1 * 4 + l4;
                xf[mf] = *reinterpret_cast<const short8*>(&a_lds[cur][row * 128 + ((g * 16) ^ ((row & 7) << 4))]);
            }
            #pragma unroll
            for (int mf = 0; mf < 4; mf++)
                #pragma unroll
                for (int nf = 0; nf < 8; nf++)
                    acc[mf][nf] = __builtin_amdgcn_mfma_f32_16x16x32_bf16(wf1[nf], xf[mf], acc[mf][nf], 0, 0, 0);
        }
        if (kt < 3) {
            __syncthreads();
            uint4 v0, v1;
            v0.x = cvt_pk2(f0.x, f0.y); v0.y = cvt_pk2(f0.z, f0.w);
            v0.z = cvt_pk2(f1.x, f1.y); v0.w = cvt_pk2(f1.z, f1.w);
            v1.x = cvt_pk2(f2.x, f2.y); v1.y = cvt_pk2(f2.z, f2.w);
            v1.z = cvt_pk2(f3.x, f3.y); v1.w = cvt_pk2(f3.z, f3.w);
            int g0 = skq * 2, g1 = skq * 2 + 1, sx = (srow & 7) << 4;
            *reinterpret_cast<uint4*>(&a_lds[cur ^ 1][srow * 128 + ((g0 * 16) ^ sx)]) = v0;
            *reinterpret_cast<uint4*>(&a_lds[cur ^ 1][srow * 128 + ((g1 * 16) ^ sx)]) = v1;
            __syncthreads();
            cur ^= 1;
        }
    }

    const int nt = l4 & 1, half = l4 >> 1;
    #pragma unroll
    for (int mf = 0; mf < 4; mf++)
        #pragma unroll
        for (int p = 0; p < 4; p++) {
            u32 pn[2][2], po[2][2];
            #pragma unroll
            for (int n = 0; n < 2; n++) {
                int nf = p * 2 + n;
                pn[n][0] = cvt_pk2(acc[mf][nf][0], acc[mf][nf][1]);
                pn[n][1] = cvt_pk2(acc[mf][nf][2], acc[mf][nf][3]);
                po[n][0] = (u32)__shfl_xor((int)pn[n][0], 16);
                po[n][1] = (u32)__shfl_xor((int)pn[n][1], 16);
            }
            u32 a0 = pn[nt][0], a1 = pn[nt][1], b0 = po[nt][0], b1 = po[nt][1];
            uint4 qv;
            if (l4 & 1) { qv.x = b0; qv.y = b1; qv.z = a0; qv.w = a1; }
            else        { qv.x = a0; qv.y = a1; qv.z = b0; qv.w = b1; }
            long row_g = rb * 64 + mf * 16 + l15;
            int c0 = w * 128 + p * 32 + nt * 16 + half * 8;
            if (c0 < 256) *reinterpret_cast<uint4*>(&kbf[row_g * 256 + c0]) = qv;
            else          *reinterpret_cast<uint4*>(&vbf[row_g * 256 + c0 - 256]) = qv;
        }
}

// ---------------- initial q = SCALE * slots @ Wq ----------------
__global__ __launch_bounds__(256) void k_qproj(const float* __restrict__ slots,
        const u32* __restrict__ wqp, float* __restrict__ q) {
    __shared__ float s_lds[256];
    int row = blockIdx.x, t = threadIdx.x;
    s_lds[t] = slots[(long)row * 256 + t];
    __syncthreads();
    float a = 0.f;
    #pragma unroll 8
    for (int d2 = 0; d2 < 128; d2++) {
        u32 w = wqp[d2 * 256 + t];
        a += bf_lo(w) * s_lds[2*d2] + bf_hi(w) * s_lds[2*d2 + 1];
    }
    q[(long)row * 256 + t] = a * SCALE_F;
}

// ---------------- MFMA flash attention ----------------
// grid (16 mc, 64 b) x 256 thr (4 waves). Per block: 4 tiles of 64 m; wave owns 16 m/tile.
// QK^T: mfma(k_frag, q_frag) -> lane holds S[m=4*l4+r][n=l15] == PV's A-frag layout.
// PV: A = [p0..p3,0,0,0,0] (zero-padded K=32), B = v duplicated 4+4, v_lds rotation-swizzled.
// Block-shared running max via LDS stats; in-block partial merge through dead k/v LDS.
__global__ __launch_bounds__(256) void k_flash(const float* __restrict__ q,
        const u16* __restrict__ kbf, const u16* __restrict__ vbf,
        float* __restrict__ part, float* __restrict__ ml) {
    __shared__ __align__(16) unsigned char smem[8192 + 65536];  // q(8K) | k(32K) | v(32K); k+v alias merge
    __shared__ float wmax_lds[4][16];
    __shared__ float lsum_lds[4][16];
    u16* q_lds = (u16*)smem;
    u16* k_lds = (u16*)(smem + 8192);
    u16* v_lds = (u16*)(smem + 8192 + 32768);
    float* mg  = (float*)(smem + 8192);

    const int b = blockIdx.y, mc = blockIdx.x, tid = threadIdx.x;
    const int w = tid >> 6, l = tid & 63, l4 = l >> 4, l15 = l & 15;
    const long kv0 = (long)b * 4096 + mc * 256;

    // stage q (f32 -> bf16, XOR-swizzled rows)
    {
        int n = tid >> 4, dq = tid & 15;
        const float* qp = q + (long)b * 4096 + n * 256 + dq * 16;
        float4 f0 = *reinterpret_cast<const float4*>(qp);
        float4 f1 = *reinterpret_cast<const float4*>(qp + 4);
        float4 f2 = *reinterpret_cast<const float4*>(qp + 8);
        float4 f3 = *reinterpret_cast<const float4*>(qp + 12);
        uint4 v0, v1;
        v0.x = cvt_pk2(f0.x, f0.y); v0.y = cvt_pk2(f0.z, f0.w);
        v0.z = cvt_pk2(f1.x, f1.y); v0.w = cvt_pk2(f1.z, f1.w);
        v1.x = cvt_pk2(f2.x, f2.y); v1.y = cvt_pk2(f2.z, f2.w);
        v1.z = cvt_pk2(f3.x, f3.y); v1.w = cvt_pk2(f3.z, f3.w);
        int sx = (n & 7) << 4;
        *reinterpret_cast<uint4*>((unsigned char*)q_lds + n * 512 + (((dq * 2) * 16) ^ sx)) = v0;
        *reinterpret_cast<uint4*>((unsigned char*)q_lds + n * 512 + (((dq * 2 + 1) * 16) ^ sx)) = v1;
    }

#define STAGE_KV(t) { \
    const u16* kb_ = kbf + (kv0 + (t) * 64) * 256; \
    const u16* vb_ = vbf + (kv0 + (t) * 64) * 256; \
    _Pragma("unroll") \
    for (int it = 0; it < 8; it++) { \
        int gid = tid + it * 256; int r_ = gid >> 5, gp_ = gid & 31; \
        int gk_ = gp_ ^ (r_ & 7); \
        int gv_ = (gp_ - 2 * ((r_ >> 2) & 3)) & 31; \
        gload16(kb_ + (long)r_ * 256 + gk_ * 8, (unsigned char*)k_lds + it * 4096 + w * 1024); \
        gload16(vb_ + (long)r_ * 256 + gv_ * 8, (unsigned char*)v_lds + it * 4096 + w * 1024); \
    } }

    STAGE_KV(0);
    __syncthreads();

    floatx4 acc[16];
    #pragma unroll
    for (int dt = 0; dt < 16; dt++) acc[dt] = (floatx4){0.f, 0.f, 0.f, 0.f};
    float mrun = NEG_BIG, lrun = 0.f;
    float mrun_q[4] = {NEG_BIG, NEG_BIG, NEG_BIG, NEG_BIG};

    const int mrow = w * 16 + l15;          // QK A-frag row (k matrix row)
    const int vm0 = w * 16 + 4 * l4;        // PV v rows base
    const int vcol0 = l15 + 16 * l4;        // rotated column base

    #pragma unroll 1
    for (int t = 0; t < 4; t++) {
        // ---- QK^T: 8 K-steps ----
        floatx4 s = (floatx4){0.f, 0.f, 0.f, 0.f};
        #pragma unroll
        for (int ks = 0; ks < 8; ks++) {
            int g = ks * 4 + l4;
            short8 ka = *reinterpret_cast<const short8*>(
                (unsigned char*)k_lds + mrow * 512 + ((g * 16) ^ ((mrow & 7) << 4)));
            short8 qb = *reinterpret_cast<const short8*>(
                (unsigned char*)q_lds + l15 * 512 + ((g * 16) ^ ((l15 & 7) << 4)));
            s = __builtin_amdgcn_mfma_f32_16x16x32_bf16(ka, qb, s, 0, 0, 0);
        }
        // ---- wave max per n over its 16 m ----
        float wm = fmaxf(fmaxf(s[0], s[1]), fmaxf(s[2], s[3]));
        wm = fmaxf(wm, __shfl_xor(wm, 16));
        wm = fmaxf(wm, __shfl_xor(wm, 32));
        if (l < 16) wmax_lds[w][l15] = wm;
        __syncthreads();   // B1: stats visible
        // ---- block max, softmax (n = l15 side) ----
        float tmo = fmaxf(fmaxf(wmax_lds[0][l15], wmax_lds[1][l15]),
                          fmaxf(wmax_lds[2][l15], wmax_lds[3][l15]));
        float mn = fmaxf(mrun, tmo);
        float sc = __expf(mrun - mn); mrun = mn;
        float p0 = __expf(s[0] - mn), p1 = __expf(s[1] - mn);
        float p2 = __expf(s[2] - mn), p3 = __expf(s[3] - mn);
        float ps = p0 + p1 + p2 + p3;
        ps += __shfl_xor(ps, 16); ps += __shfl_xor(ps, 32);
        lrun = lrun * sc + ps;
        // ---- acc-side stats (n = 4*l4+r) + rescale ----
        float scq[4];
        #pragma unroll
        for (int r = 0; r < 4; r++) {
            int nq = 4 * l4 + r;
            float tq = fmaxf(fmaxf(wmax_lds[0][nq], wmax_lds[1][nq]),
                             fmaxf(wmax_lds[2][nq], wmax_lds[3][nq]));
            float mnq = fmaxf(mrun_q[r], tq);
            scq[r] = __expf(mrun_q[r] - mnq); mrun_q[r] = mnq;
        }
        #pragma unroll
        for (int dt = 0; dt < 16; dt++) {
            acc[dt][0] *= scq[0]; acc[dt][1] *= scq[1];
            acc[dt][2] *= scq[2]; acc[dt][3] *= scq[3];
        }
        // ---- pack P to bf16 A-frag (zero-padded upper K) ----
        union { short8 s8; u32 u[4]; } pu;
        pu.u[0] = cvt_pk2(p0, p1); pu.u[1] = cvt_pk2(p2, p3);
        pu.u[2] = 0; pu.u[3] = 0;
        short8 pa = pu.s8;
        // ---- PV: 16 d-tiles ----
        #pragma unroll
        for (int dt = 0; dt < 16; dt++) {
            int col = (dt * 16 + vcol0) & 255;
            u16 v0 = v_lds[(vm0 + 0) * 256 + col];
            u16 v1 = v_lds[(vm0 + 1) * 256 + col];
            u16 v2 = v_lds[(vm0 + 2) * 256 + col];
            u16 v3 = v_lds[(vm0 + 3) * 256 + col];
            union { short8 s8; u16 h[8]; } vu;
            vu.h[0] = v0; vu.h[1] = v1; vu.h[2] = v2; vu.h[3] = v3;
            vu.h[4] = v0; vu.h[5] = v1; vu.h[6] = v2; vu.h[7] = v3;
            acc[dt] = __builtin_amdgcn_mfma_f32_16x16x32_bf16(pa, vu.s8, acc[dt], 0, 0, 0);
        }
        __syncthreads();   // B2: tile t reads done
        if (t < 3) {
            STAGE_KV(t + 1);
            __syncthreads();   // B3: staged visible (drains vmcnt)
        }
    }
#undef STAGE_KV

    // ---- in-block merge: waves share same scale (block-wide max) -> plain sum ----
    #pragma unroll
    for (int dt = 0; dt < 16; dt++)
        #pragma unroll
        for (int r = 0; r < 4; r++)
            mg[w * 4096 + (4 * l4 + r) * 256 + dt * 16 + l15] = acc[dt][r];
    if (l < 16) lsum_lds[w][l15] = lrun;
    __syncthreads();
    #pragma unroll
    for (int i = 0; i < 4; i++) {
        int gid = tid + i * 256;
        int n = gid >> 6, dq = gid & 63;
        float4 a0 = *reinterpret_cast<const float4*>(&mg[n * 256 + dq * 4]);
        float4 a1 = *reinterpret_cast<const float4*>(&mg[4096 + n * 256 + dq * 4]);
        float4 a2 = *reinterpret_cast<const float4*>(&mg[8192 + n * 256 + dq * 4]);
        float4 a3 = *reinterpret_cast<const float4*>(&mg[12288 + n * 256 + dq * 4]);
        float4 o;
        o.x = a0.x + a1.x + a2.x + a3.x;
        o.y = a0.y + a1.y + a2.y + a3.y;
        o.z = a0.z + a1.z + a2.z + a3.z;
        o.w = a0.w + a1.w + a2.w + a3.w;
        *reinterpret_cast<float4*>(&part[(((long)b * 16 + mc) * 16 + n) * 256 + dq * 4]) = o;
    }
    if (tid < 16) {
        long base = (((long)b * 16 + mc) * 16 + tid) * 2;
        ml[base + 0] = mrun;   // wave0 lane tid holds mrun for n = tid
        ml[base + 1] = lsum_lds[0][tid] + lsum_lds[1][tid] + lsum_lds[2][tid] + lsum_lds[3][tid];
    }
}

// ---------------- fused merge + GRU + LayerNorm + MLP residual + next-q; 2 rows/block ----------------
__global__ __launch_bounds__(256) void k_gru(const float* __restrict__ part, const float* __restrict__ ml,
        float* __restrict__ slots,
        const u32* __restrict__ wgh, const float* __restrict__ b_ih, const float* __restrict__ b_hh,
        const float* __restrict__ ln_g, const float* __restrict__ ln_b,
        const u32* __restrict__ w1p, const float* __restrict__ b1,
        const u32* __restrict__ w2p, const float* __restrict__ b2,
        const u32* __restrict__ wqp, float* __restrict__ qout) {
    __shared__ float u_lds[2][256], s_lds[2][256], h_lds[2][256], hm_lds[2][512], sf_lds[2][256];
    __shared__ float red[2][4][2];
    int t = threadIdx.x;
    int row0 = blockIdx.x * 2;
    int b = row0 >> 4, n0 = row0 & 15;
    #pragma unroll
    for (int rr = 0; rr < 2; rr++) {
        int n = n0 + rr;
        const float* mlp = ml + ((long)b * 256 + n) * 2;
        float M = NEG_BIG;
        float mv[16], lv[16];
        #pragma unroll
        for (int c = 0; c < 16; c++) { mv[c] = mlp[c * 32]; lv[c] = mlp[c * 32 + 1]; M = fmaxf(M, mv[c]); }
        float ec[16], denom = 0.f;
        #pragma unroll
        for (int c = 0; c < 16; c++) { ec[c] = __expf(mv[c] - M); denom += ec[c] * lv[c]; }
        float inv = 1.f / denom;
        float u = 0.f;
        #pragma unroll
        for (int c = 0; c < 16; c++)
            u += part[(((long)b * 16 + c) * 16 + n) * 256 + t] * ec[c];
        u_lds[rr][t] = u * inv;
        s_lds[rr][t] = slots[(long)(row0 + rr) * 256 + t];
    }
    __syncthreads();
    float gxr[2] = {0,0}, gxz[2] = {0,0}, gxn[2] = {0,0};
    float ghr[2] = {0,0}, ghz[2] = {0,0}, ghn[2] = {0,0};
    #pragma unroll 4
    for (int d = 0; d < 256; d++) {
        u32 p0 = wgh[d * 768 + t], p1 = wgh[d * 768 + 256 + t], p2 = wgh[d * 768 + 512 + t];
        float wir = bf_lo(p0), whr = bf_hi(p0);
        float wiz = bf_lo(p1), whz = bf_hi(p1);
        float win = bf_lo(p2), whn = bf_hi(p2);
        #pragma unroll
        for (int rr = 0; rr < 2; rr++) {
            float ud = u_lds[rr][d], sd = s_lds[rr][d];
            gxr[rr] += ud * wir; ghr[rr] += sd * whr;
            gxz[rr] += ud * wiz; ghz[rr] += sd * whz;
            gxn[rr] += ud * win; ghn[rr] += sd * whn;
        }
    }
    float bir = b_ih[t], biz = b_ih[t + 256], bin = b_ih[t + 512];
    float bhr = b_hh[t], bhz = b_hh[t + 256], bhn = b_hh[t + 512];
    float snew[2];
    int wv = t >> 6, lnid = t & 63;
    #pragma unroll
    for (int rr = 0; rr < 2; rr++) {
        float r = 1.f / (1.f + expf(-(gxr[rr] + bir + ghr[rr] + bhr)));
        float z = 1.f / (1.f + expf(-(gxz[rr] + biz + ghz[rr] + bhz)));
        float nn = tanhf(gxn[rr] + bin + r * (ghn[rr] + bhn));
        snew[rr] = (1.f - z) * nn + z * s_lds[rr][t];
        float sm = snew[rr], sq = snew[rr] * snew[rr];
        #pragma unroll
        for (int off = 32; off > 0; off >>= 1) { sm += __shfl_xor(sm, off); sq += __shfl_xor(sq, off); }
        if (lnid == 0) { red[rr][wv][0] = sm; red[rr][wv][1] = sq; }
    }
    __syncthreads();
    float lng = ln_g[t], lnb = ln_b[t];
    #pragma unroll
    for (int rr = 0; rr < 2; rr++) {
        float sm = red[rr][0][0] + red[rr][1][0] + red[rr][2][0] + red[rr][3][0];
        float sq = red[rr][0][1] + red[rr][1][1] + red[rr][2][1] + red[rr][3][1];
        float mu = sm * (1.f / 256.f);
        float var = sq * (1.f / 256.f) - mu * mu;
        float rs = rsqrtf(var + LN_EPS_F);
        h_lds[rr][t] = (snew[rr] - mu) * rs * lng + lnb;
    }
    __syncthreads();
    float m1a[2] = {0,0}, m1b[2] = {0,0};
    #pragma unroll 4
    for (int d = 0; d < 256; d++) {
        u32 wp = w1p[d * 256 + t];
        float wa = bf_lo(wp), wb = bf_hi(wp);
        #pragma unroll
        for (int rr = 0; rr < 2; rr++) { float hd = h_lds[rr][d]; m1a[rr] += hd * wa; m1b[rr] += hd * wb; }
    }
    float b1a = b1[t], b1b = b1[t + 256];
    #pragma unroll
    for (int rr = 0; rr < 2; rr++) {
        float xa = m1a[rr] + b1a, xb = m1b[rr] + b1b;
        hm_lds[rr][t]       = 0.5f * xa * (1.f + erff(xa * 0.70710678118654752f));
        hm_lds[rr][t + 256] = 0.5f * xb * (1.f + erff(xb * 0.70710678118654752f));
    }
    __syncthreads();
    float m2[2] = {0,0};
    #pragma unroll 4
    for (int d2 = 0; d2 < 256; d2++) {
        u32 wp = w2p[d2 * 256 + t];
        #pragma unroll
        for (int rr = 0; rr < 2; rr++)
            m2[rr] += bf_lo(wp) * hm_lds[rr][2*d2] + bf_hi(wp) * hm_lds[rr][2*d2 + 1];
    }
    float b2v = b2[t];
    #pragma unroll
    for (int rr = 0; rr < 2; rr++) {
        float sf = snew[rr] + m2[rr] + b2v;
        slots[(long)(row0 + rr) * 256 + t] = sf;
        sf_lds[rr][t] = sf;
    }
    __syncthreads();
    float qa[2] = {0,0};
    #pragma unroll 4
    for (int d2 = 0; d2 < 128; d2++) {
        u32 wp = wqp[d2 * 256 + t];
        #pragma unroll
        for (int rr = 0; rr < 2; rr++)
            qa[rr] += bf_lo(wp) * sf_lds[rr][2*d2] + bf_hi(wp) * sf_lds[rr][2*d2 + 1];
    }
    #pragma unroll
    for (int rr = 0; rr < 2; rr++)
        qout[(long)(row0 + rr) * 256 + t] = qa[rr] * SCALE_F;
}

extern "C" void kernel_launch(void* const* d_in, const int* in_sizes, int n_in,
                              void* d_out, int out_size, void* d_ws, size_t ws_size,
                              hipStream_t stream) {
    const float* inputs  = (const float*)d_in[0];
    const float* noise   = (const float*)d_in[1];
    const float* slot_mu = (const float*)d_in[2];
    const float* slot_ls = (const float*)d_in[3];
    const float* Wq   = (const float*)d_in[4];
    const float* Wk   = (const float*)d_in[5];
    const float* Wv   = (const float*)d_in[6];
    const float* W_ih = (const float*)d_in[7];
    const float* W_hh = (const float*)d_in[8];
    const float* b_ih = (const float*)d_in[9];
    const float* b_hh = (const float*)d_in[10];
    const float* ln_g = (const float*)d_in[11];
    const float* ln_b = (const float*)d_in[12];
    const float* W1   = (const float*)d_in[13];
    const float* b1   = (const float*)d_in[14];
    const float* W2   = (const float*)d_in[15];
    const float* b2   = (const float*)d_in[16];
    float* slots = (float*)d_out;

    char* ws = (char*)d_ws;
    u16*   kbf  = (u16*)  (ws);                    // 134217728
    u16*   vbf  = (u16*)  (ws + 134217728);        // 134217728
    float* q    = (float*)(ws + 268435456);        // 1048576
    float* part = (float*)(ws + 269484032);        // 16777216
    float* ml   = (float*)(ws + 286261248);        // 131072
    u16*   w_t  = (u16*)  (ws + 286392320);        // 262144
    u32*   wgh  = (u32*)  (ws + 286654464);        // 786432
    u32*   wqp  = (u32*)  (ws + 287440896);        // 131072
    u32*   w1p  = (u32*)  (ws + 287571968);        // 262144
    u32*   w2p  = (u32*)  (ws + 287834112);        // 262144

    k_prep<<<dim3(2944), dim3(256), 0, stream>>>(noise, slot_mu, slot_ls, Wq, Wk, Wv,
            W_ih, W_hh, W1, W2, slots, w_t, wqp, wgh, w1p, w2p);
    k_gemm_kv<<<dim3(4096), dim3(256), 0, stream>>>(inputs, w_t, kbf, vbf);
    k_qproj<<<dim3(1024), dim3(256), 0, stream>>>(slots, wqp, q);
    for (int it = 0; it < 3; it++) {
        k_flash<<<dim3(16, 64), dim3(256), 0, stream>>>(q, kbf, vbf, part, ml);
        k_gru<<<dim3(512), dim3(256), 0, stream>>>(part, ml, slots,
                wgh, b_ih, b_hh, ln_g, ln_b, w1p, b1, w2p, b2, wqp, q);
    }
}